// Round 1
// baseline (31083.389 us; speedup 1.0000x reference)
//
#include <hip/hip_runtime.h>
#include <hip/hip_cooperative_groups.h>

namespace cg = cooperative_groups;

#define HDIM   256
#define NLAYER 10
#define BATCH  256
#define TSTEPS 512

typedef __attribute__((ext_vector_type(8))) short short8;
typedef __attribute__((ext_vector_type(4))) float f32x4;

// ---------- bf16 helpers (bit-level, no header API dependence) ----------
__device__ __forceinline__ unsigned short bf16_rne(float f) {
    unsigned u = __float_as_uint(f);
    unsigned r = u + 0x7FFFu + ((u >> 16) & 1u);
    return (unsigned short)(r >> 16);
}
__device__ __forceinline__ float bf16_f(unsigned short b) {
    return __uint_as_float(((unsigned)b) << 16);
}

// ---------- prep: convert weights/bias/h0 to hi/lo bf16 ----------
__global__ void prep_kernel(const float* __restrict__ Wx_w, const float* __restrict__ Wx_b,
                            const float* __restrict__ Wh_w, const float* __restrict__ Wh_b,
                            const float* __restrict__ hidden0,
                            unsigned short* __restrict__ Wx_hi, unsigned short* __restrict__ Wx_lo,
                            unsigned short* __restrict__ Wh_hi, unsigned short* __restrict__ Wh_lo,
                            float* __restrict__ bias,
                            unsigned short* __restrict__ Hb_hi, unsigned short* __restrict__ Hb_lo) {
    int i = blockIdx.x * 256 + threadIdx.x;
    const int WELEM = NLAYER * HDIM * HDIM;   // == NLAYER*BATCH*HDIM
    if (i >= WELEM) return;
    {
        float v = Wx_w[i];
        unsigned short h = bf16_rne(v);
        Wx_hi[i] = h;
        Wx_lo[i] = bf16_rne(v - bf16_f(h));
    }
    {
        float v = Wh_w[i];
        unsigned short h = bf16_rne(v);
        Wh_hi[i] = h;
        Wh_lo[i] = bf16_rne(v - bf16_f(h));
    }
    {
        float v = hidden0[i];                 // plane 0 of Hb (parity of t=0 read)
        unsigned short h = bf16_rne(v);
        Hb_hi[i] = h;
        Hb_lo[i] = bf16_rne(v - bf16_f(h));
    }
    if (i < NLAYER * HDIM) bias[i] = Wx_b[i] + Wh_b[i];
}

// ---------- inner GEMM panels ----------
#define MFMA16(a, b, c) __builtin_amdgcn_mfma_f32_16x16x32_bf16((a), (b), (c), 0, 0, 0)

__device__ __forceinline__ void mfma12(const short8& ah0, const short8& al0,
                                       const short8& ah1, const short8& al1,
                                       const short8& bh0, const short8& bl0,
                                       const short8& bh1, const short8& bl1,
                                       f32x4 acc[2][2]) {
    acc[0][0] = MFMA16(ah0, bh0, acc[0][0]);
    acc[0][1] = MFMA16(ah0, bh1, acc[0][1]);
    acc[1][0] = MFMA16(ah1, bh0, acc[1][0]);
    acc[1][1] = MFMA16(ah1, bh1, acc[1][1]);
    acc[0][0] = MFMA16(ah0, bl0, acc[0][0]);
    acc[0][1] = MFMA16(ah0, bl1, acc[0][1]);
    acc[1][0] = MFMA16(ah1, bl0, acc[1][0]);
    acc[1][1] = MFMA16(ah1, bl1, acc[1][1]);
    acc[0][0] = MFMA16(al0, bh0, acc[0][0]);
    acc[0][1] = MFMA16(al0, bh1, acc[0][1]);
    acc[1][0] = MFMA16(al1, bh0, acc[1][0]);
    acc[1][1] = MFMA16(al1, bh1, acc[1][1]);
}

// A (activations, bf16 hi/lo, row-major [BATCH][HDIM]) x B (weights W[i][j], row-major,
// used as Bmat[k=j][col=i] so an 8-elem frag = 8 consecutive j of W row i).
__device__ __forceinline__ void gemm_panel_bf(
    const unsigned short* __restrict__ Ahi, const unsigned short* __restrict__ Alo,
    const unsigned short* __restrict__ Bhi, const unsigned short* __restrict__ Blo,
    int row0, int col0, int kgrp, f32x4 acc[2][2]) {
#pragma unroll
    for (int kc = 0; kc < HDIM; kc += 32) {
        const int k = kc + kgrp;
        short8 ah0 = *(const short8*)(Ahi + (size_t)row0 * HDIM + k);
        short8 ah1 = *(const short8*)(Ahi + (size_t)(row0 + 16) * HDIM + k);
        short8 al0 = *(const short8*)(Alo + (size_t)row0 * HDIM + k);
        short8 al1 = *(const short8*)(Alo + (size_t)(row0 + 16) * HDIM + k);
        short8 bh0 = *(const short8*)(Bhi + (size_t)col0 * HDIM + k);
        short8 bh1 = *(const short8*)(Bhi + (size_t)(col0 + 16) * HDIM + k);
        short8 bl0 = *(const short8*)(Blo + (size_t)col0 * HDIM + k);
        short8 bl1 = *(const short8*)(Blo + (size_t)(col0 + 16) * HDIM + k);
        mfma12(ah0, al0, ah1, al1, bh0, bl0, bh1, bl1, acc);
    }
}

__device__ __forceinline__ void cvt8(const float* __restrict__ p, short8& hi, short8& lo) {
#pragma unroll
    for (int e = 0; e < 8; ++e) {
        float f = p[e];
        unsigned short h = bf16_rne(f);
        hi[e] = (short)h;
        lo[e] = (short)bf16_rne(f - bf16_f(h));
    }
}

// layer-0 x panel: A rows gathered from fp32 embedding, converted in-register
__device__ __forceinline__ void gemm_panel_emb(
    const float* __restrict__ e0, const float* __restrict__ e1,
    const unsigned short* __restrict__ Bhi, const unsigned short* __restrict__ Blo,
    int col0, int kgrp, f32x4 acc[2][2]) {
#pragma unroll
    for (int kc = 0; kc < HDIM; kc += 32) {
        const int k = kc + kgrp;
        short8 ah0, al0, ah1, al1;
        cvt8(e0 + k, ah0, al0);
        cvt8(e1 + k, ah1, al1);
        short8 bh0 = *(const short8*)(Bhi + (size_t)col0 * HDIM + k);
        short8 bh1 = *(const short8*)(Bhi + (size_t)(col0 + 16) * HDIM + k);
        short8 bl0 = *(const short8*)(Blo + (size_t)col0 * HDIM + k);
        short8 bl1 = *(const short8*)(Blo + (size_t)(col0 + 16) * HDIM + k);
        mfma12(ah0, al0, ah1, al1, bh0, bl0, bh1, bl1, acc);
    }
}

// ---------- main cooperative kernel: diagonal wavefront ----------
// grid = 160 wgs: wg g -> layer l=g/16, 64x64 output tile (g%16) of the [256,256] layer-step.
// 4 waves/wg, each computes a 32x32 quadrant (2x2 of 16x16 MFMA tiles).
__global__ void __launch_bounds__(256, 1) rnn_main(
    const int* __restrict__ tokens, const float* __restrict__ emb,
    const unsigned short* __restrict__ Wx_hi, const unsigned short* __restrict__ Wx_lo,
    const unsigned short* __restrict__ Wh_hi, const unsigned short* __restrict__ Wh_lo,
    const float* __restrict__ bias,
    unsigned short* __restrict__ Hb_hi, unsigned short* __restrict__ Hb_lo,
    unsigned short* __restrict__ Xb_hi, unsigned short* __restrict__ Xb_lo,
    float* __restrict__ out) {
    const int g = blockIdx.x;
    const int l = g >> 4;
    const int tile = g & 15;
    const int tile_m = (tile >> 2) << 6;
    const int tile_n = (tile & 3) << 6;
    const int tid = threadIdx.x;
    const int wave = tid >> 6;
    const int lane = tid & 63;
    const int wm = (wave >> 1) << 5;
    const int wn = (wave & 1) << 5;
    const int row0 = tile_m + wm + (lane & 15);
    const int col0 = tile_n + wn + (lane & 15);
    const int kgrp = (lane >> 4) << 3;
    const int PLANE = NLAYER * BATCH * HDIM;

    float* hfinal = out + (size_t)BATCH * TSTEPS * HDIM;

    const unsigned short* wxh = Wx_hi + l * HDIM * HDIM;
    const unsigned short* wxl = Wx_lo + l * HDIM * HDIM;
    const unsigned short* whh = Wh_hi + l * HDIM * HDIM;
    const unsigned short* whl = Wh_lo + l * HDIM * HDIM;

    cg::grid_group grid = cg::this_grid();

    for (int d = 0; d < TSTEPS + NLAYER - 1; ++d) {
        const int t = d - l;
        if (t >= 0 && t < TSTEPS) {
            f32x4 acc[2][2] = {};
            // ---- x @ Wx^T ----
            if (l == 0) {
                const int tok0 = tokens[row0 * TSTEPS + t];
                const int tok1 = tokens[(row0 + 16) * TSTEPS + t];
                gemm_panel_emb(emb + (size_t)tok0 * HDIM, emb + (size_t)tok1 * HDIM,
                               wxh, wxl, col0, kgrp, acc);
            } else {
                const unsigned short* xh = Xb_hi + (size_t)(d & 1) * PLANE + l * BATCH * HDIM;
                const unsigned short* xl = Xb_lo + (size_t)(d & 1) * PLANE + l * BATCH * HDIM;
                gemm_panel_bf(xh, xl, wxh, wxl, row0, col0, kgrp, acc);
            }
            // ---- h @ Wh^T ----
            {
                const unsigned short* hh = Hb_hi + (size_t)(t & 1) * PLANE + l * BATCH * HDIM;
                const unsigned short* hl = Hb_lo + (size_t)(t & 1) * PLANE + l * BATCH * HDIM;
                gemm_panel_bf(hh, hl, whh, whl, row0, col0, kgrp, acc);
            }
            // ---- epilogue: bias, tanh, publish ----
            unsigned short* nhh = Hb_hi + (size_t)((t + 1) & 1) * PLANE + l * BATCH * HDIM;
            unsigned short* nhl = Hb_lo + (size_t)((t + 1) & 1) * PLANE + l * BATCH * HDIM;
            unsigned short* nxh = Xb_hi + (size_t)((d + 1) & 1) * PLANE + (l + 1) * BATCH * HDIM;
            unsigned short* nxl = Xb_lo + (size_t)((d + 1) & 1) * PLANE + (l + 1) * BATCH * HDIM;
#pragma unroll
            for (int ni = 0; ni < 2; ++ni) {
                const int colg = tile_n + wn + ni * 16 + (lane & 15);
                const float bv = bias[l * HDIM + colg];
#pragma unroll
                for (int mi = 0; mi < 2; ++mi) {
#pragma unroll
                    for (int r = 0; r < 4; ++r) {
                        const int rowg = tile_m + wm + mi * 16 + ((lane >> 4) << 2) + r;
                        const float y = tanhf(acc[mi][ni][r] + bv);
                        const unsigned short yh = bf16_rne(y);
                        const unsigned short yl = bf16_rne(y - bf16_f(yh));
                        nhh[rowg * HDIM + colg] = yh;
                        nhl[rowg * HDIM + colg] = yl;
                        if (l < NLAYER - 1) {
                            nxh[rowg * HDIM + colg] = yh;
                            nxl[rowg * HDIM + colg] = yl;
                        } else {
                            out[((size_t)rowg * TSTEPS + t) * HDIM + colg] = y;
                        }
                        if (t == TSTEPS - 1) hfinal[(l * BATCH + rowg) * HDIM + colg] = y;
                    }
                }
            }
        }
        __threadfence();   // device-scope release before cross-XCD consumption
        grid.sync();
    }
}

// ---------- host ----------
extern "C" void kernel_launch(void* const* d_in, const int* in_sizes, int n_in,
                              void* d_out, int out_size, void* d_ws, size_t ws_size,
                              hipStream_t stream) {
    const int* tokens = (const int*)d_in[0];
    const float* hidden0 = (const float*)d_in[1];
    const float* emb = (const float*)d_in[2];
    const float* Wx_w = (const float*)d_in[3];
    const float* Wx_b = (const float*)d_in[4];
    const float* Wh_w = (const float*)d_in[5];
    const float* Wh_b = (const float*)d_in[6];
    float* out = (float*)d_out;

    char* ws = (char*)d_ws;
    size_t off = 0;
    auto carve = [&](size_t bytes) -> void* {
        void* p = ws + off;
        off = (off + bytes + 255) & ~(size_t)255;
        return p;
    };
    const size_t WELEM = (size_t)NLAYER * HDIM * HDIM;   // 655,360 (== L*B*H)
    unsigned short* Wx_hi = (unsigned short*)carve(WELEM * 2);
    unsigned short* Wx_lo = (unsigned short*)carve(WELEM * 2);
    unsigned short* Wh_hi = (unsigned short*)carve(WELEM * 2);
    unsigned short* Wh_lo = (unsigned short*)carve(WELEM * 2);
    float* bias = (float*)carve((size_t)NLAYER * HDIM * 4);
    unsigned short* Hb_hi = (unsigned short*)carve(2 * WELEM * 2);
    unsigned short* Hb_lo = (unsigned short*)carve(2 * WELEM * 2);
    unsigned short* Xb_hi = (unsigned short*)carve(2 * WELEM * 2);
    unsigned short* Xb_lo = (unsigned short*)carve(2 * WELEM * 2);
    (void)ws_size; (void)in_sizes; (void)n_in; (void)out_size;

    hipLaunchKernelGGL(prep_kernel, dim3((unsigned)((WELEM + 255) / 256)), dim3(256), 0, stream,
                       Wx_w, Wx_b, Wh_w, Wh_b, hidden0,
                       Wx_hi, Wx_lo, Wh_hi, Wh_lo, bias, Hb_hi, Hb_lo);

    void* args[] = { (void*)&tokens, (void*)&emb,
                     (void*)&Wx_hi, (void*)&Wx_lo, (void*)&Wh_hi, (void*)&Wh_lo,
                     (void*)&bias, (void*)&Hb_hi, (void*)&Hb_lo, (void*)&Xb_hi, (void*)&Xb_lo,
                     (void*)&out };
    hipLaunchCooperativeKernel((void*)rnn_main, dim3(160), dim3(256), args, 0, stream);
}

// Round 2
// 24363.551 us; speedup vs baseline: 1.2758x; 1.2758x over previous
//
#include <hip/hip_runtime.h>
#include <hip/hip_cooperative_groups.h>

namespace cg = cooperative_groups;

#define HDIM   256
#define NLAYER 10
#define BATCH  256
#define TSTEPS 512
#define NTILE  8                       // per layer: 2 (M=128) x 4 (N=64)
#define NWG    (NLAYER * NTILE)        // 80
#define NTHR   512                     // 8 waves: 4m x 2n of 32x32

typedef __attribute__((ext_vector_type(8))) short short8;
typedef __attribute__((ext_vector_type(4))) float f32x4;

// ---------- bf16 helpers ----------
__device__ __forceinline__ unsigned short bf16_rne(float f) {
    unsigned u = __float_as_uint(f);
    unsigned r = u + 0x7FFFu + ((u >> 16) & 1u);
    return (unsigned short)(r >> 16);
}
__device__ __forceinline__ float bf16_f(unsigned short b) {
    return __uint_as_float(((unsigned)b) << 16);
}

// ---------- prep: weights/bias/h0 -> hi/lo bf16 ----------
__global__ void prep_kernel(const float* __restrict__ Wx_w, const float* __restrict__ Wx_b,
                            const float* __restrict__ Wh_w, const float* __restrict__ Wh_b,
                            const float* __restrict__ hidden0,
                            unsigned short* __restrict__ Wx_hi, unsigned short* __restrict__ Wx_lo,
                            unsigned short* __restrict__ Wh_hi, unsigned short* __restrict__ Wh_lo,
                            float* __restrict__ bias,
                            unsigned short* __restrict__ Hb_hi, unsigned short* __restrict__ Hb_lo) {
    int i = blockIdx.x * 256 + threadIdx.x;
    const int WELEM = NLAYER * HDIM * HDIM;
    if (i >= WELEM) return;
    {
        float v = Wx_w[i];
        unsigned short h = bf16_rne(v);
        Wx_hi[i] = h;
        Wx_lo[i] = bf16_rne(v - bf16_f(h));
    }
    {
        float v = Wh_w[i];
        unsigned short h = bf16_rne(v);
        Wh_hi[i] = h;
        Wh_lo[i] = bf16_rne(v - bf16_f(h));
    }
    {
        float v = hidden0[i];              // plane 0 of Hb (read at t=0)
        unsigned short h = bf16_rne(v);
        Hb_hi[i] = h;
        Hb_lo[i] = bf16_rne(v - bf16_f(h));
    }
    if (i < NLAYER * HDIM) bias[i] = Wx_b[i] + Wh_b[i];
}

// ---------- MFMA helpers ----------
#define MFMA16(a, b, c) __builtin_amdgcn_mfma_f32_16x16x32_bf16((a), (b), (c), 0, 0, 0)

__device__ __forceinline__ void mfma12(const short8& ah0, const short8& al0,
                                       const short8& ah1, const short8& al1,
                                       const short8& bh0, const short8& bl0,
                                       const short8& bh1, const short8& bl1,
                                       f32x4 acc[2][2]) {
    acc[0][0] = MFMA16(ah0, bh0, acc[0][0]);
    acc[0][1] = MFMA16(ah0, bh1, acc[0][1]);
    acc[1][0] = MFMA16(ah1, bh0, acc[1][0]);
    acc[1][1] = MFMA16(ah1, bh1, acc[1][1]);
    acc[0][0] = MFMA16(ah0, bl0, acc[0][0]);
    acc[0][1] = MFMA16(ah0, bl1, acc[0][1]);
    acc[1][0] = MFMA16(ah1, bl0, acc[1][0]);
    acc[1][1] = MFMA16(ah1, bl1, acc[1][1]);
    acc[0][0] = MFMA16(al0, bh0, acc[0][0]);
    acc[0][1] = MFMA16(al0, bh1, acc[0][1]);
    acc[1][0] = MFMA16(al1, bh0, acc[1][0]);
    acc[1][1] = MFMA16(al1, bh1, acc[1][1]);
}

// LDS weight fragment read, XOR-swizzled (byte ^= (row&7)<<4; reads are 16B-aligned units)
__device__ __forceinline__ short8 ldw(const unsigned short* __restrict__ w,
                                      int arr, int c, int k) {
    return *(const short8*)((const char*)w + arr * 32768 + c * 512 +
                            ((2 * k) ^ ((c & 7) << 4)));
}

// A (activations hi/lo, global, row-major [BATCH][HDIM]) x B (weights from LDS)
__device__ __forceinline__ void gemm_panel_lds(
    const unsigned short* __restrict__ Ahi, const unsigned short* __restrict__ Alo,
    const unsigned short* __restrict__ wlds, int warr,
    int row0, int cl0, int kgrp, f32x4 acc[2][2]) {
#pragma unroll
    for (int kc = 0; kc < HDIM; kc += 32) {
        const int k = kc + kgrp;
        short8 ah0 = *(const short8*)(Ahi + (size_t)row0 * HDIM + k);
        short8 ah1 = *(const short8*)(Ahi + (size_t)(row0 + 16) * HDIM + k);
        short8 al0 = *(const short8*)(Alo + (size_t)row0 * HDIM + k);
        short8 al1 = *(const short8*)(Alo + (size_t)(row0 + 16) * HDIM + k);
        short8 bh0 = ldw(wlds, warr, cl0, k);
        short8 bh1 = ldw(wlds, warr, cl0 + 16, k);
        short8 bl0 = ldw(wlds, warr + 1, cl0, k);
        short8 bl1 = ldw(wlds, warr + 1, cl0 + 16, k);
        mfma12(ah0, al0, ah1, al1, bh0, bl0, bh1, bl1, acc);
    }
}

__device__ __forceinline__ void cvt8(const float* __restrict__ p, short8& hi, short8& lo) {
#pragma unroll
    for (int e = 0; e < 8; ++e) {
        float f = p[e];
        unsigned short h = bf16_rne(f);
        hi[e] = (short)h;
        lo[e] = (short)bf16_rne(f - bf16_f(h));
    }
}

// layer-0 x panel: A rows gathered from fp32 embedding, converted in-register
__device__ __forceinline__ void gemm_panel_emb(
    const float* __restrict__ e0, const float* __restrict__ e1,
    const unsigned short* __restrict__ wlds,
    int cl0, int kgrp, f32x4 acc[2][2]) {
#pragma unroll
    for (int kc = 0; kc < HDIM; kc += 32) {
        const int k = kc + kgrp;
        short8 ah0, al0, ah1, al1;
        cvt8(e0 + k, ah0, al0);
        cvt8(e1 + k, ah1, al1);
        short8 bh0 = ldw(wlds, 0, cl0, k);
        short8 bh1 = ldw(wlds, 0, cl0 + 16, k);
        short8 bl0 = ldw(wlds, 1, cl0, k);
        short8 bl1 = ldw(wlds, 1, cl0 + 16, k);
        mfma12(ah0, al0, ah1, al1, bh0, bl0, bh1, bl1, acc);
    }
}

// ---------- main cooperative kernel: diagonal wavefront, LDS-resident weights ----------
// wg g: layer l=g/8, tile (g%8): tile_m = (g%8)/4*128, tile_n = (g%8)%4*64.
// 8 waves: wave computes 32x32; wm = (wave>>1)*32, wn = (wave&1)*32.
__global__ void __launch_bounds__(NTHR, 1) rnn_main(
    const int* __restrict__ tokens, const float* __restrict__ emb,
    const unsigned short* __restrict__ Wx_hi, const unsigned short* __restrict__ Wx_lo,
    const unsigned short* __restrict__ Wh_hi, const unsigned short* __restrict__ Wh_lo,
    const float* __restrict__ bias,
    unsigned short* __restrict__ Hb_hi, unsigned short* __restrict__ Hb_lo,
    unsigned short* __restrict__ Xb_hi, unsigned short* __restrict__ Xb_lo,
    float* __restrict__ out) {
    const int g = blockIdx.x;
    const int l = g >> 3;
    const int tile = g & 7;
    const int tile_m = (tile >> 2) << 7;       // 0 or 128
    const int tile_n = (tile & 3) << 6;        // 0,64,128,192
    const int tid = threadIdx.x;
    const int wave = tid >> 6;
    const int lane = tid & 63;
    const int wm = (wave >> 1) << 5;           // 0..96
    const int wn = (wave & 1) << 5;            // 0 or 32
    const int row0 = tile_m + wm + (lane & 15);
    const int cl0 = wn + (lane & 15);          // tile-local output col
    const int kgrp = (lane >> 4) << 3;
    const int PLANE = NLAYER * BATCH * HDIM;

    // ---- stage this wg's weight slice into LDS (once), XOR-swizzled ----
    __shared__ unsigned short w_lds[4 * 64 * 256];   // 128 KB: [arr][row 64][k 256]
    {
        const size_t loff = (size_t)l * HDIM * HDIM;
        const unsigned short* srcs[4] = { Wx_hi + loff, Wx_lo + loff,
                                          Wh_hi + loff, Wh_lo + loff };
#pragma unroll
        for (int a = 0; a < 4; ++a) {
            for (int c = tid; c < 2048; c += NTHR) {   // 2048 x 16B chunks per array
                const int r = c >> 5;                  // 0..63 (output col within tile)
                const int kb = c & 31;                 // 16B chunk within row
                const short8 v = *(const short8*)(srcs[a] +
                                  (size_t)(tile_n + r) * HDIM + kb * 8);
                *(short8*)((char*)w_lds + a * 32768 + r * 512 +
                           ((kb * 16) ^ ((r & 7) << 4))) = v;
            }
        }
    }
    __syncthreads();

    // bias per output col is fixed per thread: hoist to registers
    float bv[2];
#pragma unroll
    for (int ni = 0; ni < 2; ++ni)
        bv[ni] = bias[l * HDIM + tile_n + wn + ni * 16 + (lane & 15)];

    float* hfinal = out + (size_t)BATCH * TSTEPS * HDIM;

    cg::grid_group grid = cg::this_grid();

    for (int d = 0; d < TSTEPS + NLAYER - 1; ++d) {
        const int t = d - l;
        if (t >= 0 && t < TSTEPS) {
            f32x4 acc[2][2] = {};
            // ---- x @ Wx^T ----
            if (l == 0) {
                const int tok0 = tokens[row0 * TSTEPS + t];
                const int tok1 = tokens[(row0 + 16) * TSTEPS + t];
                gemm_panel_emb(emb + (size_t)tok0 * HDIM, emb + (size_t)tok1 * HDIM,
                               w_lds, cl0, kgrp, acc);
            } else {
                const unsigned short* xh = Xb_hi + (size_t)(d & 1) * PLANE + l * BATCH * HDIM;
                const unsigned short* xl = Xb_lo + (size_t)(d & 1) * PLANE + l * BATCH * HDIM;
                gemm_panel_lds(xh, xl, w_lds, 0, row0, cl0, kgrp, acc);
            }
            // ---- h @ Wh^T ----
            {
                const unsigned short* hh = Hb_hi + (size_t)(t & 1) * PLANE + l * BATCH * HDIM;
                const unsigned short* hl = Hb_lo + (size_t)(t & 1) * PLANE + l * BATCH * HDIM;
                gemm_panel_lds(hh, hl, w_lds, 2, row0, cl0, kgrp, acc);
            }
            // ---- epilogue: bias, tanh, publish ----
            unsigned short* nhh = Hb_hi + (size_t)((t + 1) & 1) * PLANE + l * BATCH * HDIM;
            unsigned short* nhl = Hb_lo + (size_t)((t + 1) & 1) * PLANE + l * BATCH * HDIM;
            unsigned short* nxh = Xb_hi + (size_t)((d + 1) & 1) * PLANE + (l + 1) * BATCH * HDIM;
            unsigned short* nxl = Xb_lo + (size_t)((d + 1) & 1) * PLANE + (l + 1) * BATCH * HDIM;
#pragma unroll
            for (int ni = 0; ni < 2; ++ni) {
                const int colg = tile_n + wn + ni * 16 + (lane & 15);
#pragma unroll
                for (int mi = 0; mi < 2; ++mi) {
#pragma unroll
                    for (int r = 0; r < 4; ++r) {
                        const int rowg = tile_m + wm + mi * 16 + ((lane >> 4) << 2) + r;
                        const float y = tanhf(acc[mi][ni][r] + bv[ni]);
                        const unsigned short yh = bf16_rne(y);
                        const unsigned short yl = bf16_rne(y - bf16_f(yh));
                        nhh[rowg * HDIM + colg] = yh;
                        nhl[rowg * HDIM + colg] = yl;
                        if (l < NLAYER - 1) {
                            nxh[rowg * HDIM + colg] = yh;
                            nxl[rowg * HDIM + colg] = yl;
                        } else {
                            out[((size_t)rowg * TSTEPS + t) * HDIM + colg] = y;
                        }
                        if (t == TSTEPS - 1) hfinal[(l * BATCH + rowg) * HDIM + colg] = y;
                    }
                }
            }
        }
        __threadfence();   // device-scope release before cross-XCD consumption
        grid.sync();
    }
}

// ---------- host ----------
extern "C" void kernel_launch(void* const* d_in, const int* in_sizes, int n_in,
                              void* d_out, int out_size, void* d_ws, size_t ws_size,
                              hipStream_t stream) {
    const int* tokens = (const int*)d_in[0];
    const float* hidden0 = (const float*)d_in[1];
    const float* emb = (const float*)d_in[2];
    const float* Wx_w = (const float*)d_in[3];
    const float* Wx_b = (const float*)d_in[4];
    const float* Wh_w = (const float*)d_in[5];
    const float* Wh_b = (const float*)d_in[6];
    float* out = (float*)d_out;

    char* ws = (char*)d_ws;
    size_t off = 0;
    auto carve = [&](size_t bytes) -> void* {
        void* p = ws + off;
        off = (off + bytes + 255) & ~(size_t)255;
        return p;
    };
    const size_t WELEM = (size_t)NLAYER * HDIM * HDIM;   // 655,360 (== L*B*H)
    unsigned short* Wx_hi = (unsigned short*)carve(WELEM * 2);
    unsigned short* Wx_lo = (unsigned short*)carve(WELEM * 2);
    unsigned short* Wh_hi = (unsigned short*)carve(WELEM * 2);
    unsigned short* Wh_lo = (unsigned short*)carve(WELEM * 2);
    float* bias = (float*)carve((size_t)NLAYER * HDIM * 4);
    unsigned short* Hb_hi = (unsigned short*)carve(2 * WELEM * 2);
    unsigned short* Hb_lo = (unsigned short*)carve(2 * WELEM * 2);
    unsigned short* Xb_hi = (unsigned short*)carve(2 * WELEM * 2);
    unsigned short* Xb_lo = (unsigned short*)carve(2 * WELEM * 2);
    (void)ws_size; (void)in_sizes; (void)n_in; (void)out_size;

    hipLaunchKernelGGL(prep_kernel, dim3((unsigned)((WELEM + 255) / 256)), dim3(256), 0, stream,
                       Wx_w, Wx_b, Wh_w, Wh_b, hidden0,
                       Wx_hi, Wx_lo, Wh_hi, Wh_lo, bias, Hb_hi, Hb_lo);

    void* args[] = { (void*)&tokens, (void*)&emb,
                     (void*)&Wx_hi, (void*)&Wx_lo, (void*)&Wh_hi, (void*)&Wh_lo,
                     (void*)&bias, (void*)&Hb_hi, (void*)&Hb_lo, (void*)&Xb_hi, (void*)&Xb_lo,
                     (void*)&out };
    hipLaunchCooperativeKernel((void*)rnn_main, dim3(NWG), dim3(NTHR), args, 0, stream);
}

// Round 3
// 10631.146 us; speedup vs baseline: 2.9238x; 2.2917x over previous
//
#include <hip/hip_runtime.h>

#define HDIM   256
#define NLAYER 10
#define BATCH  256
#define TSTEPS 512
#define NTILE  8                       // per layer: 2 (M=128) x 4 (N=64)
#define NWG    (NLAYER * NTILE)        // 80
#define NTHR   512                     // 8 waves: 4m x 2n of 32x32

typedef __attribute__((ext_vector_type(8))) short short8;
typedef __attribute__((ext_vector_type(4))) float f32x4;

// ---------- bf16 helpers ----------
__device__ __forceinline__ unsigned short bf16_rne(float f) {
    unsigned u = __float_as_uint(f);
    unsigned r = u + 0x7FFFu + ((u >> 16) & 1u);
    return (unsigned short)(r >> 16);
}
__device__ __forceinline__ float bf16_f(unsigned short b) {
    return __uint_as_float(((unsigned)b) << 16);
}
// overflow-safe fast tanh: tanh(v) = sign(v) * (1-e^{-2|v|})/(1+e^{-2|v|})
__device__ __forceinline__ float fast_tanh(float v) {
    float a = fabsf(v);
    float e = __expf(-2.0f * a);
    float r = (1.0f - e) / (1.0f + e);
    return __builtin_copysignf(r, v);
}

// ---------- prep: weights/bias/h0 -> hi/lo bf16 ----------
__global__ void prep_kernel(const float* __restrict__ Wx_w, const float* __restrict__ Wx_b,
                            const float* __restrict__ Wh_w, const float* __restrict__ Wh_b,
                            const float* __restrict__ hidden0,
                            unsigned short* __restrict__ Wx_hi, unsigned short* __restrict__ Wx_lo,
                            unsigned short* __restrict__ Wh_hi, unsigned short* __restrict__ Wh_lo,
                            float* __restrict__ bias,
                            unsigned short* __restrict__ Hb_hi, unsigned short* __restrict__ Hb_lo) {
    int i = blockIdx.x * 256 + threadIdx.x;
    const int WELEM = NLAYER * HDIM * HDIM;
    if (i >= WELEM) return;
    {
        float v = Wx_w[i];
        unsigned short h = bf16_rne(v);
        Wx_hi[i] = h;
        Wx_lo[i] = bf16_rne(v - bf16_f(h));
    }
    {
        float v = Wh_w[i];
        unsigned short h = bf16_rne(v);
        Wh_hi[i] = h;
        Wh_lo[i] = bf16_rne(v - bf16_f(h));
    }
    {
        float v = hidden0[i];              // h0 -> H plane 0 (read at t=0)
        unsigned short h = bf16_rne(v);
        Hb_hi[i] = h;
        Hb_lo[i] = bf16_rne(v - bf16_f(h));
    }
    if (i < NLAYER * HDIM) bias[i] = Wx_b[i] + Wh_b[i];
}

// ---------- MFMA helpers ----------
#define MFMA16(a, b, c) __builtin_amdgcn_mfma_f32_16x16x32_bf16((a), (b), (c), 0, 0, 0)

__device__ __forceinline__ void mfma12(const short8& ah0, const short8& al0,
                                       const short8& ah1, const short8& al1,
                                       const short8& bh0, const short8& bl0,
                                       const short8& bh1, const short8& bl1,
                                       f32x4 acc[2][2]) {
    acc[0][0] = MFMA16(ah0, bh0, acc[0][0]);
    acc[0][1] = MFMA16(ah0, bh1, acc[0][1]);
    acc[1][0] = MFMA16(ah1, bh0, acc[1][0]);
    acc[1][1] = MFMA16(ah1, bh1, acc[1][1]);
    acc[0][0] = MFMA16(ah0, bl0, acc[0][0]);
    acc[0][1] = MFMA16(ah0, bl1, acc[0][1]);
    acc[1][0] = MFMA16(ah1, bl0, acc[1][0]);
    acc[1][1] = MFMA16(ah1, bl1, acc[1][1]);
    acc[0][0] = MFMA16(al0, bh0, acc[0][0]);
    acc[0][1] = MFMA16(al0, bh1, acc[0][1]);
    acc[1][0] = MFMA16(al1, bh0, acc[1][0]);
    acc[1][1] = MFMA16(al1, bh1, acc[1][1]);
}

// LDS weight fragment read, XOR-swizzled
__device__ __forceinline__ short8 ldw(const unsigned short* __restrict__ w,
                                      int arr, int c, int k) {
    return *(const short8*)((const char*)w + arr * 32768 + c * 512 +
                            ((2 * k) ^ ((c & 7) << 4)));
}

// A (activations hi/lo, global, row-major [BATCH][HDIM]) x B (weights from LDS)
__device__ __forceinline__ void gemm_panel_lds(
    const unsigned short* __restrict__ Ahi, const unsigned short* __restrict__ Alo,
    const unsigned short* __restrict__ wlds, int warr,
    int row0, int cl0, int kgrp, f32x4 acc[2][2]) {
#pragma unroll
    for (int kc = 0; kc < HDIM; kc += 32) {
        const int k = kc + kgrp;
        short8 ah0 = *(const short8*)(Ahi + (size_t)row0 * HDIM + k);
        short8 ah1 = *(const short8*)(Ahi + (size_t)(row0 + 16) * HDIM + k);
        short8 al0 = *(const short8*)(Alo + (size_t)row0 * HDIM + k);
        short8 al1 = *(const short8*)(Alo + (size_t)(row0 + 16) * HDIM + k);
        short8 bh0 = ldw(wlds, warr, cl0, k);
        short8 bh1 = ldw(wlds, warr, cl0 + 16, k);
        short8 bl0 = ldw(wlds, warr + 1, cl0, k);
        short8 bl1 = ldw(wlds, warr + 1, cl0 + 16, k);
        mfma12(ah0, al0, ah1, al1, bh0, bl0, bh1, bl1, acc);
    }
}

__device__ __forceinline__ void cvt8(const float* __restrict__ p, short8& hi, short8& lo) {
#pragma unroll
    for (int e = 0; e < 8; ++e) {
        float f = p[e];
        unsigned short h = bf16_rne(f);
        hi[e] = (short)h;
        lo[e] = (short)bf16_rne(f - bf16_f(h));
    }
}

// layer-0 x panel: A rows gathered from fp32 embedding, converted in-register
__device__ __forceinline__ void gemm_panel_emb(
    const float* __restrict__ e0, const float* __restrict__ e1,
    const unsigned short* __restrict__ wlds,
    int cl0, int kgrp, f32x4 acc[2][2]) {
#pragma unroll
    for (int kc = 0; kc < HDIM; kc += 32) {
        const int k = kc + kgrp;
        short8 ah0, al0, ah1, al1;
        cvt8(e0 + k, ah0, al0);
        cvt8(e1 + k, ah1, al1);
        short8 bh0 = ldw(wlds, 0, cl0, k);
        short8 bh1 = ldw(wlds, 0, cl0 + 16, k);
        short8 bl0 = ldw(wlds, 1, cl0, k);
        short8 bl1 = ldw(wlds, 1, cl0 + 16, k);
        mfma12(ah0, al0, ah1, al1, bh0, bl0, bh1, bl1, acc);
    }
}

// ---------- flag spin helpers (agent scope; relaxed poll + one acquire) ----------
__device__ __forceinline__ void wait_ge(int* f, int need) {
    while (__hip_atomic_load(f, __ATOMIC_RELAXED, __HIP_MEMORY_SCOPE_AGENT) < need)
        __builtin_amdgcn_s_sleep(1);
}

// ---------- main kernel: flag-pipelined diagonal wavefront ----------
// wg g: layer l=g/8, tile: tile_m = ((g%8)/4)*128, tile_n = ((g%8)%4)*64.
// Each wg iterates its OWN t=0..511, gated on flags. No grid.sync.
// x(t) for layer l is read directly from layer l-1's H plane ((t+1)&1).
__global__ void __launch_bounds__(NTHR, 1) rnn_main(
    const int* __restrict__ tokens, const float* __restrict__ emb,
    const unsigned short* __restrict__ Wx_hi, const unsigned short* __restrict__ Wx_lo,
    const unsigned short* __restrict__ Wh_hi, const unsigned short* __restrict__ Wh_lo,
    const float* __restrict__ bias,
    unsigned short* __restrict__ Hb_hi, unsigned short* __restrict__ Hb_lo,
    int* __restrict__ flagH,
    float* __restrict__ out) {
    const int g = blockIdx.x;
    const int l = g >> 3;
    const int tile = g & 7;
    const int mb = tile >> 2;                  // m-block 0/1
    const int tile_m = mb << 7;                // 0 or 128
    const int tile_n = (tile & 3) << 6;        // 0,64,128,192
    const int tid = threadIdx.x;
    const int wave = tid >> 6;
    const int lane = tid & 63;
    const int wm = (wave >> 1) << 5;           // 0..96
    const int wn = (wave & 1) << 5;            // 0 or 32
    const int row0 = tile_m + wm + (lane & 15);
    const int cl0 = wn + (lane & 15);          // tile-local output col
    const int kgrp = (lane >> 4) << 3;
    const int PLANE = NLAYER * BATCH * HDIM;

    // ---- stage this wg's weight slice into LDS (once), XOR-swizzled ----
    __shared__ unsigned short w_lds[4 * 64 * 256];   // 128 KB
    {
        const size_t loff = (size_t)l * HDIM * HDIM;
        const unsigned short* srcs[4] = { Wx_hi + loff, Wx_lo + loff,
                                          Wh_hi + loff, Wh_lo + loff };
#pragma unroll
        for (int a = 0; a < 4; ++a) {
            for (int c = tid; c < 2048; c += NTHR) {
                const int r = c >> 5;
                const int kb = c & 31;
                const short8 v = *(const short8*)(srcs[a] +
                                  (size_t)(tile_n + r) * HDIM + kb * 8);
                *(short8*)((char*)w_lds + a * 32768 + r * 512 +
                           ((kb * 16) ^ ((r & 7) << 4))) = v;
            }
        }
    }
    __syncthreads();

    float bv[2];
#pragma unroll
    for (int ni = 0; ni < 2; ++ni)
        bv[ni] = bias[l * HDIM + tile_n + wn + ni * 16 + (lane & 15)];

    float* hfinal = out + (size_t)BATCH * TSTEPS * HDIM;

    int* fx  = (l > 0) ? &flagH[(((l - 1) * 2 + mb) * TSTEPS)] : nullptr;   // x-ready
    int* fh  = &flagH[((l * 2 + mb) * TSTEPS)];                             // h-ready / own
    int* fwar = (l < NLAYER - 1) ? &flagH[(((l + 1) * 2 + mb) * TSTEPS)] : nullptr;

    for (int t = 0; t < TSTEPS; ++t) {
        // ---- wait for inputs (and WAR guard), then acquire-invalidate ----
        if (tid == 0) {
            if (l > 0) wait_ge(fx + t, 4);                 // x(t) = h(t,l-1) ready
            if (t > 0) wait_ge(fh + t - 1, 4);             // h(t-1,l) ready
            if (fwar && t >= 2) wait_ge(fwar + t - 2, 4);  // plane reuse safe
            (void)__hip_atomic_load(fh + t, __ATOMIC_ACQUIRE, __HIP_MEMORY_SCOPE_AGENT);
        }
        __syncthreads();

        f32x4 acc[2][2] = {};
        // ---- x @ Wx^T ----
        if (l == 0) {
            const int tok0 = tokens[row0 * TSTEPS + t];
            const int tok1 = tokens[(row0 + 16) * TSTEPS + t];
            gemm_panel_emb(emb + (size_t)tok0 * HDIM, emb + (size_t)tok1 * HDIM,
                           w_lds, cl0, kgrp, acc);
        } else {
            const unsigned short* xh = Hb_hi + (size_t)((t + 1) & 1) * PLANE + (l - 1) * BATCH * HDIM;
            const unsigned short* xl = Hb_lo + (size_t)((t + 1) & 1) * PLANE + (l - 1) * BATCH * HDIM;
            gemm_panel_lds(xh, xl, w_lds, 0, row0, cl0, kgrp, acc);
        }
        // ---- h @ Wh^T ----
        {
            const unsigned short* hh = Hb_hi + (size_t)(t & 1) * PLANE + l * BATCH * HDIM;
            const unsigned short* hl = Hb_lo + (size_t)(t & 1) * PLANE + l * BATCH * HDIM;
            gemm_panel_lds(hh, hl, w_lds, 2, row0, cl0, kgrp, acc);
        }
        // ---- epilogue: bias, tanh, publish h(t) to plane (t+1)&1 ----
        unsigned short* nhh = Hb_hi + (size_t)((t + 1) & 1) * PLANE + l * BATCH * HDIM;
        unsigned short* nhl = Hb_lo + (size_t)((t + 1) & 1) * PLANE + l * BATCH * HDIM;
#pragma unroll
        for (int ni = 0; ni < 2; ++ni) {
            const int colg = tile_n + wn + ni * 16 + (lane & 15);
#pragma unroll
            for (int mi = 0; mi < 2; ++mi) {
#pragma unroll
                for (int r = 0; r < 4; ++r) {
                    const int rowg = tile_m + wm + mi * 16 + ((lane >> 4) << 2) + r;
                    const float y = fast_tanh(acc[mi][ni][r] + bv[ni]);
                    const unsigned short yh = bf16_rne(y);
                    const unsigned short yl = bf16_rne(y - bf16_f(yh));
                    nhh[rowg * HDIM + colg] = yh;
                    nhl[rowg * HDIM + colg] = yl;
                    if (l == NLAYER - 1)
                        out[((size_t)rowg * TSTEPS + t) * HDIM + colg] = y;
                    if (t == TSTEPS - 1)
                        hfinal[(l * BATCH + rowg) * HDIM + colg] = y;
                }
            }
        }
        __syncthreads();   // all stores vmcnt-complete (in L2)
        if (tid == 0)      // release: L2 writeback then flag bump
            __hip_atomic_fetch_add(fh + t, 1, __ATOMIC_RELEASE, __HIP_MEMORY_SCOPE_AGENT);
    }
}

// ---------- host ----------
extern "C" void kernel_launch(void* const* d_in, const int* in_sizes, int n_in,
                              void* d_out, int out_size, void* d_ws, size_t ws_size,
                              hipStream_t stream) {
    const int* tokens = (const int*)d_in[0];
    const float* hidden0 = (const float*)d_in[1];
    const float* emb = (const float*)d_in[2];
    const float* Wx_w = (const float*)d_in[3];
    const float* Wx_b = (const float*)d_in[4];
    const float* Wh_w = (const float*)d_in[5];
    const float* Wh_b = (const float*)d_in[6];
    float* out = (float*)d_out;

    char* ws = (char*)d_ws;
    size_t off = 0;
    auto carve = [&](size_t bytes) -> void* {
        void* p = ws + off;
        off = (off + bytes + 255) & ~(size_t)255;
        return p;
    };
    const size_t WELEM = (size_t)NLAYER * HDIM * HDIM;   // 655,360 (== L*B*H)
    unsigned short* Wx_hi = (unsigned short*)carve(WELEM * 2);
    unsigned short* Wx_lo = (unsigned short*)carve(WELEM * 2);
    unsigned short* Wh_hi = (unsigned short*)carve(WELEM * 2);
    unsigned short* Wh_lo = (unsigned short*)carve(WELEM * 2);
    float* bias = (float*)carve((size_t)NLAYER * HDIM * 4);
    unsigned short* Hb_hi = (unsigned short*)carve(2 * WELEM * 2);
    unsigned short* Hb_lo = (unsigned short*)carve(2 * WELEM * 2);
    const size_t FLAGN = (size_t)NLAYER * 2 * TSTEPS;
    int* flagH = (int*)carve(FLAGN * 4);
    (void)ws_size; (void)in_sizes; (void)n_in; (void)out_size;

    hipMemsetAsync(flagH, 0, FLAGN * 4, stream);

    hipLaunchKernelGGL(prep_kernel, dim3((unsigned)((WELEM + 255) / 256)), dim3(256), 0, stream,
                       Wx_w, Wx_b, Wh_w, Wh_b, hidden0,
                       Wx_hi, Wx_lo, Wh_hi, Wh_lo, bias, Hb_hi, Hb_lo);

    void* args[] = { (void*)&tokens, (void*)&emb,
                     (void*)&Wx_hi, (void*)&Wx_lo, (void*)&Wh_hi, (void*)&Wh_lo,
                     (void*)&bias, (void*)&Hb_hi, (void*)&Hb_lo, (void*)&flagH,
                     (void*)&out };
    hipLaunchCooperativeKernel((void*)rnn_main, dim3(NWG), dim3(NTHR), args, 0, stream);
}

// Round 4
// 8400.345 us; speedup vs baseline: 3.7003x; 1.2656x over previous
//
#include <hip/hip_runtime.h>

#define HDIM   256
#define NLAYER 10
#define BATCH  256
#define TSTEPS 512
#define NSLICE 8                 // batch slices
#define MROWS  32                // rows per slice
#define NTHR   512               // 8 waves; wave w owns output cols [32w, 32w+32)
#define NEPOCH (TSTEPS / 2)      // 2 t-steps per flag epoch
#define NB_REC (NLAYER * NSLICE) // 80 recurrence wgs
#define NB_ALL (2 * NB_REC)      // + 80 feed wgs

typedef __attribute__((ext_vector_type(8))) short short8;
typedef __attribute__((ext_vector_type(4))) float f32x4;

// ---------- bf16 helpers ----------
__device__ __forceinline__ unsigned short bf16_rne(float f) {
    unsigned u = __float_as_uint(f);
    unsigned r = u + 0x7FFFu + ((u >> 16) & 1u);
    return (unsigned short)(r >> 16);
}
__device__ __forceinline__ float bf16_f(unsigned short b) {
    return __uint_as_float(((unsigned)b) << 16);
}
__device__ __forceinline__ float fast_tanh(float v) {
    float a = fabsf(v);
    float e = __expf(-2.0f * a);
    float r = (1.0f - e) / (1.0f + e);
    return __builtin_copysignf(r, v);
}
__device__ __forceinline__ void cvt8(const float* __restrict__ p, short8& hi, short8& lo) {
#pragma unroll
    for (int e = 0; e < 8; ++e) {
        float f = p[e];
        unsigned short h = bf16_rne(f);
        hi[e] = (short)h;
        lo[e] = (short)bf16_rne(f - bf16_f(h));
    }
}

#define MFMA16(a, b, c) __builtin_amdgcn_mfma_f32_16x16x32_bf16((a), (b), (c), 0, 0, 0)

// 12-MFMA hi/lo triple product for one kc: A {ah0,ah1,al0,al1} x B {bh0,bh1,bl0,bl1}
#define MFMA12(ah0, ah1, al0, al1, bh0, bh1, bl0, bl1, acc)  \
    do {                                                     \
        acc[0][0] = MFMA16(ah0, bh0, acc[0][0]);             \
        acc[1][0] = MFMA16(ah1, bh0, acc[1][0]);             \
        acc[0][1] = MFMA16(ah0, bh1, acc[0][1]);             \
        acc[1][1] = MFMA16(ah1, bh1, acc[1][1]);             \
        acc[0][0] = MFMA16(ah0, bl0, acc[0][0]);             \
        acc[1][0] = MFMA16(ah1, bl0, acc[1][0]);             \
        acc[0][1] = MFMA16(ah0, bl1, acc[0][1]);             \
        acc[1][1] = MFMA16(ah1, bl1, acc[1][1]);             \
        acc[0][0] = MFMA16(al0, bh0, acc[0][0]);             \
        acc[1][0] = MFMA16(al1, bh0, acc[1][0]);             \
        acc[0][1] = MFMA16(al0, bh1, acc[0][1]);             \
        acc[1][1] = MFMA16(al1, bh1, acc[1][1]);             \
    } while (0)

__device__ __forceinline__ void wait_ge(int* f, int need) {
    while (__hip_atomic_load(f, __ATOMIC_RELAXED, __HIP_MEMORY_SCOPE_AGENT) < need)
        __builtin_amdgcn_s_sleep(1);
}

// LDS byte layout (160 KB):
//   [0, 131072)       : W_hi swizzled, [c 256][k 256] bf16: c*512 + ((2k)^((c&7)<<4))
//   [131072, 147456)  : h_hi (rec wgs), [row 32][k 256]: same swizzle per row
//   [147456, 163840)  : h_lo
#define HHI 131072
#define HLO 147456

// stage 256x256 fp32 weight matrix -> LDS bf16-hi (swizzled), on-the-fly convert
__device__ __forceinline__ void stage_whi_f32(const float* __restrict__ src, char* smem, int tid) {
    for (int i = 0; i < 16; ++i) {
        const int c = tid + i * NTHR;          // 8192 chunks of 8 elems
        const int r = c >> 5;
        const int kb = c & 31;
        short8 hi, lo;
        cvt8(src + (size_t)r * HDIM + kb * 8, hi, lo);
        *(short8*)(smem + r * 512 + ((kb * 16) ^ ((r & 7) << 4))) = hi;
    }
}

// ---------- the single cooperative kernel, two roles ----------
__global__ void __launch_bounds__(NTHR, 1) rnn_pipe(
    const int* __restrict__ tokens, const float* __restrict__ hidden0,
    const float* __restrict__ emb,
    const float* __restrict__ Wx_w, const float* __restrict__ Wx_b,
    const float* __restrict__ Wh_w, const float* __restrict__ Wh_b,
    float* __restrict__ u,                     // [l][s][par2] frag-linear fp32 (2048 f32x4 each)
    unsigned short* __restrict__ hg_hi,        // [par2][l][s][32][256]
    unsigned short* __restrict__ hg_lo,
    int* __restrict__ fuE, int* __restrict__ fhE,   // [l*8+s][NEPOCH]
    float* __restrict__ out) {
    const int bid = blockIdx.x;
    const bool isRec = bid < NB_REC;
    const int id = isRec ? bid : bid - NB_REC;
    const int l = id >> 3;
    const int s = id & 7;
    const int tid = threadIdx.x;
    const int wv = tid >> 6;
    const int lane = tid & 63;
    const int ln15 = lane & 15;
    const int swz = (ln15 & 7) << 4;
    const int hi16 = (lane >> 4) << 4;         // k byte sub-offset
    const int kq = (lane >> 4) << 3;           // k element sub-offset

    __shared__ char smem[163840];

    float* hfinal = out + (size_t)BATCH * TSTEPS * HDIM;
    f32x4* uptr = (f32x4*)u;
    const size_t WOFF = (size_t)l * HDIM * HDIM;

    // ---------- init: stage weights ----------
    short8 wlo[2][8];                          // lo-weights for this wave's 2 n-subtiles
    {
        const float* wsrc = isRec ? (Wh_w + WOFF) : (Wx_w + WOFF);
        stage_whi_f32(wsrc, smem, tid);
#pragma unroll
        for (int ni = 0; ni < 2; ++ni) {
            const int c = wv * 32 + ni * 16 + ln15;
#pragma unroll
            for (int kc = 0; kc < 8; ++kc) {
                short8 hi, lo;
                cvt8(wsrc + (size_t)c * HDIM + kc * 32 + kq, hi, lo);
                wlo[ni][kc] = lo;
            }
        }
    }
    // rec wgs: stage h(-1) = hidden0 slice into LDS hi/lo (swizzled)
    if (isRec) {
        for (int i = tid; i < MROWS * 32; i += NTHR) {
            const int r = i >> 5;
            const int kb = i & 31;
            short8 hi, lo;
            cvt8(hidden0 + ((size_t)(l * BATCH + s * MROWS + r)) * HDIM + kb * 8, hi, lo);
            const int so = r * 512 + ((kb * 16) ^ ((r & 7) << 4));
            *(short8*)(smem + HHI + so) = hi;
            *(short8*)(smem + HLO + so) = lo;
        }
    }
    // feed wgs: bias per output col
    float bv[2];
#pragma unroll
    for (int ni = 0; ni < 2; ++ni) {
        const int col = wv * 32 + ni * 16 + ln15;
        bv[ni] = Wx_b[l * HDIM + col] + Wh_b[l * HDIM + col];
    }
    __syncthreads();

    int* myfu = fuE + id * NEPOCH;
    int* myfh = fhE + id * NEPOCH;

    if (isRec) {
        // ================= recurrence stage =================
        for (int e = 0; e < NEPOCH; ++e) {
            if (tid == 0) {
                wait_ge(myfu + e, 1);                                   // u(2e), u(2e+1) ready
                if (l < NLAYER - 1 && e > 0)
                    wait_ge(fuE + ((l + 1) * 8 + s) * NEPOCH + e - 1, 1); // hg WAR
                (void)__hip_atomic_load(myfu + e, __ATOMIC_ACQUIRE, __HIP_MEMORY_SCOPE_AGENT);
            }
            __syncthreads();
#pragma unroll
            for (int t2 = 0; t2 < 2; ++t2) {
                const int t = 2 * e + t2;
                const int par = t & 1;
                // acc <- u (frag-linear, coalesced)
                const f32x4* up = uptr + ((size_t)(id * 2 + par)) * 2048;
                f32x4 acc[2][2];
#pragma unroll
                for (int mi = 0; mi < 2; ++mi)
#pragma unroll
                    for (int ni = 0; ni < 2; ++ni)
                        acc[mi][ni] = up[(((wv * 2 + ni) * 2 + mi) << 6) + lane];
                // h(t-1) @ Wh^T from LDS/regs
#pragma unroll
                for (int kc = 0; kc < 8; ++kc) {
                    const int kb = (kc * 64 + hi16) ^ swz;
                    const short8 ah0 = *(const short8*)(smem + HHI + ln15 * 512 + kb);
                    const short8 ah1 = *(const short8*)(smem + HHI + (16 + ln15) * 512 + kb);
                    const short8 al0 = *(const short8*)(smem + HLO + ln15 * 512 + kb);
                    const short8 al1 = *(const short8*)(smem + HLO + (16 + ln15) * 512 + kb);
                    const short8 bh0 = *(const short8*)(smem + (wv * 32 + ln15) * 512 + kb);
                    const short8 bh1 = *(const short8*)(smem + (wv * 32 + 16 + ln15) * 512 + kb);
                    MFMA12(ah0, ah1, al0, al1, bh0, bh1, wlo[0][kc], wlo[1][kc], acc);
                }
                __syncthreads();   // all h(t-1) reads done before overwrite
                // epilogue: tanh, write h(t) LDS + publish
                const size_t hgo = ((size_t)(par * NB_REC + id)) * (MROWS * HDIM);
#pragma unroll
                for (int mi = 0; mi < 2; ++mi)
#pragma unroll
                    for (int ni = 0; ni < 2; ++ni) {
                        const int col = wv * 32 + ni * 16 + ln15;
#pragma unroll
                        for (int r = 0; r < 4; ++r) {
                            const int row = mi * 16 + ((lane >> 4) << 2) + r;
                            const float y = fast_tanh(acc[mi][ni][r]);
                            const unsigned short yh = bf16_rne(y);
                            const unsigned short yl = bf16_rne(y - bf16_f(yh));
                            const int so = row * 512 + ((2 * col) ^ ((row & 7) << 4));
                            *(unsigned short*)(smem + HHI + so) = yh;
                            *(unsigned short*)(smem + HLO + so) = yl;
                            if (l < NLAYER - 1) {
                                hg_hi[hgo + row * HDIM + col] = yh;
                                hg_lo[hgo + row * HDIM + col] = yl;
                            } else {
                                out[((size_t)(s * MROWS + row) * TSTEPS + t) * HDIM + col] = y;
                            }
                            if (t == TSTEPS - 1)
                                hfinal[((size_t)l * BATCH + s * MROWS + row) * HDIM + col] = y;
                        }
                    }
                __syncthreads();   // h(t) complete (and stores drained)
            }
            if (tid == 0)
                __hip_atomic_fetch_add(myfh + e, 1, __ATOMIC_RELEASE, __HIP_MEMORY_SCOPE_AGENT);
        }
    } else {
        // ================= feed stage: u(t) = x(t) @ Wx^T + b =================
        for (int e = 0; e < NEPOCH; ++e) {
            if (tid == 0) {
                if (l > 0) wait_ge(fhE + ((l - 1) * 8 + s) * NEPOCH + e, 1);  // x ready
                if (e > 0) wait_ge(myfh + e - 1, 1);                          // u WAR
                (void)__hip_atomic_load(myfh + e, __ATOMIC_ACQUIRE, __HIP_MEMORY_SCOPE_AGENT);
            }
            __syncthreads();
#pragma unroll
            for (int t2 = 0; t2 < 2; ++t2) {
                const int t = 2 * e + t2;
                const int par = t & 1;
                f32x4 acc[2][2] = {};
                if (l == 0) {
                    const int tok0 = tokens[(s * MROWS + ln15) * TSTEPS + t];
                    const int tok1 = tokens[(s * MROWS + 16 + ln15) * TSTEPS + t];
                    const float* e0 = emb + (size_t)tok0 * HDIM;
                    const float* e1 = emb + (size_t)tok1 * HDIM;
#pragma unroll
                    for (int kc = 0; kc < 8; ++kc) {
                        const int k = kc * 32 + kq;
                        short8 ah0, al0, ah1, al1;
                        cvt8(e0 + k, ah0, al0);
                        cvt8(e1 + k, ah1, al1);
                        const int kb = (kc * 64 + hi16) ^ swz;
                        const short8 bh0 = *(const short8*)(smem + (wv * 32 + ln15) * 512 + kb);
                        const short8 bh1 = *(const short8*)(smem + (wv * 32 + 16 + ln15) * 512 + kb);
                        MFMA12(ah0, ah1, al0, al1, bh0, bh1, wlo[0][kc], wlo[1][kc], acc);
                    }
                } else {
                    const size_t hgo = ((size_t)(par * NB_REC + (l - 1) * 8 + s)) * (MROWS * HDIM);
                    const unsigned short* xh = hg_hi + hgo;
                    const unsigned short* xl = hg_lo + hgo;
#pragma unroll
                    for (int kc = 0; kc < 8; ++kc) {
                        const int k = kc * 32 + kq;
                        const short8 ah0 = *(const short8*)(xh + ln15 * HDIM + k);
                        const short8 ah1 = *(const short8*)(xh + (16 + ln15) * HDIM + k);
                        const short8 al0 = *(const short8*)(xl + ln15 * HDIM + k);
                        const short8 al1 = *(const short8*)(xl + (16 + ln15) * HDIM + k);
                        const int kb = (kc * 64 + hi16) ^ swz;
                        const short8 bh0 = *(const short8*)(smem + (wv * 32 + ln15) * 512 + kb);
                        const short8 bh1 = *(const short8*)(smem + (wv * 32 + 16 + ln15) * 512 + kb);
                        MFMA12(ah0, ah1, al0, al1, bh0, bh1, wlo[0][kc], wlo[1][kc], acc);
                    }
                }
                // u = acc + bias, fragment-linear store
                f32x4* uw = uptr + ((size_t)(id * 2 + par)) * 2048;
#pragma unroll
                for (int mi = 0; mi < 2; ++mi)
#pragma unroll
                    for (int ni = 0; ni < 2; ++ni) {
                        f32x4 v = acc[mi][ni];
#pragma unroll
                        for (int r = 0; r < 4; ++r) v[r] += bv[ni];
                        uw[(((wv * 2 + ni) * 2 + mi) << 6) + lane] = v;
                    }
            }
            __syncthreads();   // drain stores
            if (tid == 0)
                __hip_atomic_fetch_add(myfu + e, 1, __ATOMIC_RELEASE, __HIP_MEMORY_SCOPE_AGENT);
        }
    }
}

// ---------- host ----------
extern "C" void kernel_launch(void* const* d_in, const int* in_sizes, int n_in,
                              void* d_out, int out_size, void* d_ws, size_t ws_size,
                              hipStream_t stream) {
    const int* tokens = (const int*)d_in[0];
    const float* hidden0 = (const float*)d_in[1];
    const float* emb = (const float*)d_in[2];
    const float* Wx_w = (const float*)d_in[3];
    const float* Wx_b = (const float*)d_in[4];
    const float* Wh_w = (const float*)d_in[5];
    const float* Wh_b = (const float*)d_in[6];
    float* out = (float*)d_out;

    char* ws = (char*)d_ws;
    size_t off = 0;
    auto carve = [&](size_t bytes) -> void* {
        void* p = ws + off;
        off = (off + bytes + 255) & ~(size_t)255;
        return p;
    };
    // u: 80 chains x 2 parity x 32x256 fp32
    float* u = (float*)carve((size_t)NB_REC * 2 * MROWS * HDIM * 4);
    // hg: 2 parity x 80 chains x 32x256 bf16 (hi, lo)
    unsigned short* hg_hi = (unsigned short*)carve((size_t)2 * NB_REC * MROWS * HDIM * 2);
    unsigned short* hg_lo = (unsigned short*)carve((size_t)2 * NB_REC * MROWS * HDIM * 2);
    int* fuE = (int*)carve((size_t)NB_REC * NEPOCH * 4);
    int* fhE = (int*)carve((size_t)NB_REC * NEPOCH * 4);
    (void)ws_size; (void)in_sizes; (void)n_in; (void)out_size;

    hipMemsetAsync(fuE, 0, (size_t)NB_REC * NEPOCH * 4 * 2, stream);  // fuE+fhE contiguous

    void* args[] = { (void*)&tokens, (void*)&hidden0, (void*)&emb,
                     (void*)&Wx_w, (void*)&Wx_b, (void*)&Wh_w, (void*)&Wh_b,
                     (void*)&u, (void*)&hg_hi, (void*)&hg_lo,
                     (void*)&fuE, (void*)&fhE, (void*)&out };
    hipLaunchCooperativeKernel((void*)rnn_pipe, dim3(NB_ALL), dim3(NTHR), args, 0, stream);
}